// Round 1
// baseline (347.295 us; speedup 1.0000x reference)
//
#include <hip/hip_runtime.h>

// Problem constants from setup_inputs(): B=8, N=8192, D=512, fp32 in/out.
#define DIM 512
#define NPB 8192  // rows per batch (N)

__device__ __forceinline__ float dot4(float4 u, float4 v) {
    return u.x * v.x + u.y * v.y + u.z * v.z + u.w * v.w;
}

// One 64-lane wave per row. Row = 512 floats = 128 float4; lane i loads
// float4[i] and float4[i+64] from each of s, h_rl, h_fk (fully coalesced,
// 16 B/lane). 5 partial dot products -> wave shuffle reduction -> lane 0
// writes the two cosine similarities.
__global__ __launch_bounds__(256) void disc_kernel(
    const float* __restrict__ s,
    const float* __restrict__ hrl,
    const float* __restrict__ hfk,
    float* __restrict__ out,
    int n_rows) {
    int gid  = blockIdx.x * blockDim.x + threadIdx.x;
    int row  = gid >> 6;
    int lane = threadIdx.x & 63;
    if (row >= n_rows) return;

    size_t base = (size_t)row * DIM;
    const float4* sp = (const float4*)(s + base);
    const float4* ap = (const float4*)(hrl + base);
    const float4* bp = (const float4*)(hfk + base);

    float4 s0 = sp[lane];
    float4 s1 = sp[lane + 64];
    float4 a0 = ap[lane];
    float4 a1 = ap[lane + 64];
    float4 b0 = bp[lane];
    float4 b1 = bp[lane + 64];

    float ss = dot4(s0, s0) + dot4(s1, s1);
    float aa = dot4(a0, a0) + dot4(a1, a1);
    float bb = dot4(b0, b0) + dot4(b1, b1);
    float sa = dot4(s0, a0) + dot4(s1, a1);
    float sb = dot4(s0, b0) + dot4(s1, b1);

    // Wave-64 reduction of the 5 sums.
    #pragma unroll
    for (int off = 32; off > 0; off >>= 1) {
        ss += __shfl_down(ss, off, 64);
        aa += __shfl_down(aa, off, 64);
        bb += __shfl_down(bb, off, 64);
        sa += __shfl_down(sa, off, 64);
        sb += __shfl_down(sb, off, 64);
    }

    if (lane == 0) {
        const float eps = 1e-12f;
        float ns = fmaxf(sqrtf(ss), eps);
        float na = fmaxf(sqrtf(aa), eps);
        float nb = fmaxf(sqrtf(bb), eps);
        int bidx = row / NPB;        // N is a power of two -> shift
        int n    = row & (NPB - 1);
        size_t obase = (size_t)bidx * (2 * NPB) + n;
        out[obase]       = sa / (ns * na);   // sc_rl
        out[obase + NPB] = sb / (ns * nb);   // sc_fk
    }
}

extern "C" void kernel_launch(void* const* d_in, const int* in_sizes, int n_in,
                              void* d_out, int out_size, void* d_ws, size_t ws_size,
                              hipStream_t stream) {
    const float* s   = (const float*)d_in[0];
    const float* hrl = (const float*)d_in[1];
    const float* hfk = (const float*)d_in[2];
    float* out = (float*)d_out;

    int n_rows = in_sizes[0] / DIM;           // B*N = 65536
    int threads = 256;                        // 4 waves/block
    int waves_per_block = threads / 64;
    int blocks = (n_rows + waves_per_block - 1) / waves_per_block;

    disc_kernel<<<blocks, threads, 0, stream>>>(s, hrl, hfk, out, n_rows);
}

// Round 2
// 324.135 us; speedup vs baseline: 1.0715x; 1.0715x over previous
//
#include <hip/hip_runtime.h>

// Problem constants from setup_inputs(): B=8, N=8192, D=512, fp32 in/out.
#define DIM 512
#define NPB 8192  // rows per batch (N)

typedef float f4 __attribute__((ext_vector_type(4)));

__device__ __forceinline__ float dot4(f4 u, f4 v) {
    f4 p = u * v;
    return p.x + p.y + p.z + p.w;
}

__device__ __forceinline__ f4 ntload(const f4* p) {
    return __builtin_nontemporal_load(p);
}

// Persistent waves, one 64-lane wave per row, grid-stride over rows with a
// 1-row software pipeline: loads for row r+1 are issued before the shuffle
// reduction of row r, so each wave keeps 6-12 global_load_dwordx4 in flight
// continuously and the DS-chain latency is hidden behind memory time.
__global__ __launch_bounds__(256) void disc_kernel(
    const float* __restrict__ s,
    const float* __restrict__ hrl,
    const float* __restrict__ hfk,
    float* __restrict__ out,
    int n_rows, int total_waves) {
    int wave = (blockIdx.x * blockDim.x + threadIdx.x) >> 6;
    int lane = threadIdx.x & 63;

    int row = wave;
    if (row >= n_rows) return;

    // Preload first row (6 x float4 per lane: [lane] and [lane+64] of each tensor).
    const f4* sp = (const f4*)(s   + (size_t)row * DIM);
    const f4* ap = (const f4*)(hrl + (size_t)row * DIM);
    const f4* bp = (const f4*)(hfk + (size_t)row * DIM);
    f4 s0 = ntload(sp + lane), s1 = ntload(sp + lane + 64);
    f4 a0 = ntload(ap + lane), a1 = ntload(ap + lane + 64);
    f4 b0 = ntload(bp + lane), b1 = ntload(bp + lane + 64);

    while (row < n_rows) {
        int nrow = row + total_waves;
        f4 t0, t1, u0, u1, v0, v1;
        if (nrow < n_rows) {
            // Issue next row's loads BEFORE reducing the current row.
            const f4* spn = (const f4*)(s   + (size_t)nrow * DIM);
            const f4* apn = (const f4*)(hrl + (size_t)nrow * DIM);
            const f4* bpn = (const f4*)(hfk + (size_t)nrow * DIM);
            t0 = ntload(spn + lane); t1 = ntload(spn + lane + 64);
            u0 = ntload(apn + lane); u1 = ntload(apn + lane + 64);
            v0 = ntload(bpn + lane); v1 = ntload(bpn + lane + 64);
        }

        float ss = dot4(s0, s0) + dot4(s1, s1);
        float aa = dot4(a0, a0) + dot4(a1, a1);
        float bb = dot4(b0, b0) + dot4(b1, b1);
        float sa = dot4(s0, a0) + dot4(s1, a1);
        float sb = dot4(s0, b0) + dot4(s1, b1);

        // Wave-64 butterfly; next row's loads are in flight during this chain.
        #pragma unroll
        for (int off = 32; off > 0; off >>= 1) {
            ss += __shfl_xor(ss, off, 64);
            aa += __shfl_xor(aa, off, 64);
            bb += __shfl_xor(bb, off, 64);
            sa += __shfl_xor(sa, off, 64);
            sb += __shfl_xor(sb, off, 64);
        }

        if (lane == 0) {
            const float eps = 1e-12f;
            float ns = fmaxf(sqrtf(ss), eps);
            float na = fmaxf(sqrtf(aa), eps);
            float nb = fmaxf(sqrtf(bb), eps);
            int bidx = row >> 13;          // row / 8192
            int n    = row & (NPB - 1);
            size_t obase = (size_t)bidx * (2 * NPB) + n;
            out[obase]       = sa / (ns * na);   // sc_rl
            out[obase + NPB] = sb / (ns * nb);   // sc_fk
        }

        // Rotate pipeline registers.
        s0 = t0; s1 = t1; a0 = u0; a1 = u1; b0 = v0; b1 = v1;
        row = nrow;
    }
}

extern "C" void kernel_launch(void* const* d_in, const int* in_sizes, int n_in,
                              void* d_out, int out_size, void* d_ws, size_t ws_size,
                              hipStream_t stream) {
    const float* s   = (const float*)d_in[0];
    const float* hrl = (const float*)d_in[1];
    const float* hfk = (const float*)d_in[2];
    float* out = (float*)d_out;

    int n_rows = in_sizes[0] / DIM;    // B*N = 65536
    int threads = 256;                 // 4 waves/block
    int blocks  = 2048;                // 8192 persistent waves -> 8 rows/wave
    int total_waves = blocks * (threads / 64);

    disc_kernel<<<blocks, threads, 0, stream>>>(s, hrl, hfk, out, n_rows, total_waves);
}

// Round 3
// 319.502 us; speedup vs baseline: 1.0870x; 1.0145x over previous
//
#include <hip/hip_runtime.h>

// Problem constants from setup_inputs(): B=8, N=8192, D=512, fp32 in/out.
#define DIM 512
#define NPB 8192   // rows per batch (N)
#define CHUNK 8    // consecutive rows owned by each wave

typedef float f4 __attribute__((ext_vector_type(4)));

__device__ __forceinline__ float dot4(f4 u, f4 v) {
    f4 p = u * v;
    return p.x + p.y + p.z + p.w;
}

__device__ __forceinline__ f4 ntload(const f4* p) {
    return __builtin_nontemporal_load(p);
}

// Persistent waves; wave w owns CHUNK consecutive rows (contiguous 16 KB
// window per tensor -> DRAM page locality). 1-row software pipeline: loads
// for row r+1 issue before the shuffle reduction of row r, keeping 6-12
// global_load_dwordx4 in flight per wave continuously.
__global__ __launch_bounds__(256) void disc_kernel(
    const float* __restrict__ s,
    const float* __restrict__ hrl,
    const float* __restrict__ hfk,
    float* __restrict__ out,
    int n_rows) {
    int wave = (blockIdx.x * blockDim.x + threadIdx.x) >> 6;
    int lane = threadIdx.x & 63;

    int row0 = wave * CHUNK;
    if (row0 >= n_rows) return;

    const f4* sp = (const f4*)(s   + (size_t)row0 * DIM);
    const f4* ap = (const f4*)(hrl + (size_t)row0 * DIM);
    const f4* bp = (const f4*)(hfk + (size_t)row0 * DIM);

    // Preload row0: 6 x float4 per lane ([lane] and [lane+64] of each tensor).
    f4 s0 = ntload(sp + lane), s1 = ntload(sp + lane + 64);
    f4 a0 = ntload(ap + lane), a1 = ntload(ap + lane + 64);
    f4 b0 = ntload(bp + lane), b1 = ntload(bp + lane + 64);

    #pragma unroll
    for (int i = 0; i < CHUNK; ++i) {
        int row = row0 + i;
        if (row >= n_rows) break;

        f4 t0, t1, u0, u1, v0, v1;
        if (i + 1 < CHUNK && row + 1 < n_rows) {
            // Next row is 128 float4 further along the same contiguous window.
            const f4* spn = sp + (size_t)(i + 1) * (DIM / 4);
            const f4* apn = ap + (size_t)(i + 1) * (DIM / 4);
            const f4* bpn = bp + (size_t)(i + 1) * (DIM / 4);
            t0 = ntload(spn + lane); t1 = ntload(spn + lane + 64);
            u0 = ntload(apn + lane); u1 = ntload(apn + lane + 64);
            v0 = ntload(bpn + lane); v1 = ntload(bpn + lane + 64);
        }

        float ss = dot4(s0, s0) + dot4(s1, s1);
        float aa = dot4(a0, a0) + dot4(a1, a1);
        float bb = dot4(b0, b0) + dot4(b1, b1);
        float sa = dot4(s0, a0) + dot4(s1, a1);
        float sb = dot4(s0, b0) + dot4(s1, b1);

        // Wave-64 butterfly; next row's loads are in flight during this chain.
        #pragma unroll
        for (int off = 32; off > 0; off >>= 1) {
            ss += __shfl_xor(ss, off, 64);
            aa += __shfl_xor(aa, off, 64);
            bb += __shfl_xor(bb, off, 64);
            sa += __shfl_xor(sa, off, 64);
            sb += __shfl_xor(sb, off, 64);
        }

        if (lane == 0) {
            const float eps = 1e-12f;
            float ns = fmaxf(sqrtf(ss), eps);
            float na = fmaxf(sqrtf(aa), eps);
            float nb = fmaxf(sqrtf(bb), eps);
            int bidx = row >> 13;          // row / 8192
            int n    = row & (NPB - 1);
            size_t obase = (size_t)bidx * (2 * NPB) + n;
            out[obase]       = sa / (ns * na);   // sc_rl
            out[obase + NPB] = sb / (ns * nb);   // sc_fk
        }

        // Rotate pipeline registers.
        s0 = t0; s1 = t1; a0 = u0; a1 = u1; b0 = v0; b1 = v1;
    }
}

extern "C" void kernel_launch(void* const* d_in, const int* in_sizes, int n_in,
                              void* d_out, int out_size, void* d_ws, size_t ws_size,
                              hipStream_t stream) {
    const float* s   = (const float*)d_in[0];
    const float* hrl = (const float*)d_in[1];
    const float* hfk = (const float*)d_in[2];
    float* out = (float*)d_out;

    int n_rows = in_sizes[0] / DIM;            // B*N = 65536
    int threads = 256;                         // 4 waves/block
    int waves_needed = (n_rows + CHUNK - 1) / CHUNK;        // 8192
    int blocks = (waves_needed + (threads / 64) - 1) / (threads / 64);  // 2048

    disc_kernel<<<blocks, threads, 0, stream>>>(s, hrl, hfk, out, n_rows);
}